// Round 4
// baseline (513.987 us; speedup 1.0000x reference)
//
#include <hip/hip_runtime.h>
#include <hip/hip_bf16.h>

// Problem constants
#define NNEUR 8192
#define NCONV 64
#define LYC   36
#define LXC   36
#define BATCH 256
#define KRAW  1296   // 36*36
#define KPAD  1344   // 21*64
#define KITER 21
#define MROWS 16384  // BATCH*NCONV
#define BM 256
#define BN 256
#define BK 64
// One staged chunk = 16 B = 8 halfs. Per tile per K-iter: 2048 chunks
// (256 rows x 8 chunks) for A and likewise for B (BN=256).
#define CH_PER_IT 2048
#define TILE_H (KITER * CH_PER_IT * 8)  // 344064 halfs per (m- or n-) tile
#define A_NTILES 64                     // 16384/256
#define B_NTILES 32                     // 8192/256
#define A_PREP_BLOCKS 10752             // 64*21*2048/256
#define B_PREP_BLOCKS 5376              // 32*21*2048/256

typedef __attribute__((ext_vector_type(8))) _Float16 half8;
typedef __attribute__((ext_vector_type(4))) float f32x4;
typedef __attribute__((ext_vector_type(16))) float f32x16;

__device__ __forceinline__ void async_copy16(const void* g, void* l) {
  __builtin_amdgcn_global_load_lds(
      (const __attribute__((address_space(1))) void*)g,
      (__attribute__((address_space(3))) void*)l, 16, 0, 0);
}

// Prep: emit A (conv->f16) and B (Wy*Wx*256->f16) in the GEMM's staged
// LDS-image order with the bank-XOR swizzle baked in: within a BK=64 row
// (8 chunks of 16 B), source chunk c sits at slot (c+row)&7. Chunk idx in
// [0,2048) -> row = idx>>3, slot = idx&7, c = (slot-row)&7.
__global__ __launch_bounds__(256) void prep_kernel(
    const float* __restrict__ conv, const float* __restrict__ Wy,
    const float* __restrict__ Wx, _Float16* __restrict__ A,
    _Float16* __restrict__ B) {
  const int t = threadIdx.x;
  half8 h;
  if (blockIdx.x < A_PREP_BLOCKS) {  // ---- A part
    const int gid = blockIdx.x * 256 + t;
    const int tile = gid / (KITER * CH_PER_IT);
    const int rem = gid - tile * (KITER * CH_PER_IT);
    const int it = rem >> 11, idx = rem & 2047;
    const int r = idx >> 3, slot = idx & 7;
    const int c = (slot - r) & 7;
    const int k0 = it * 64 + c * 8;
    const int grow = tile * BM + r;
    if (k0 < KRAW) {
      const float* s = conv + (size_t)grow * KRAW + k0;
#pragma unroll
      for (int e = 0; e < 8; e++) h[e] = (_Float16)s[e];
    } else {
#pragma unroll
      for (int e = 0; e < 8; e++) h[e] = (_Float16)0.f;
    }
    *(half8*)(A + (size_t)tile * TILE_H + (size_t)rem * 8) = h;
  } else {  // ---- B part
    const int gid = (blockIdx.x - A_PREP_BLOCKS) * 256 + t;
    const int tile = gid / (KITER * CH_PER_IT);
    const int rem = gid - tile * (KITER * CH_PER_IT);
    const int it = rem >> 11, idx = rem & 2047;
    const int r = idx >> 3, slot = idx & 7;
    const int c = (slot - r) & 7;
    const int k0 = it * 64 + c * 8;
    const int n = tile * BN + r;
#pragma unroll
    for (int e = 0; e < 8; e++) {
      const int k = k0 + e;
      float v = 0.f;
      if (k < KRAW) {
        const int y = k / LXC;
        const int x = k - y * LXC;
        v = Wy[n * LYC + y] * Wx[n * LXC + x] * 256.f;
      }
      h[e] = (_Float16)v;
    }
    *(half8*)(B + (size_t)tile * TILE_H + (size_t)rem * 8) = h;
  }
}

// Fused GEMM: block tile 256(M)x256(N), 512 threads, 8 waves (2x4), each
// wave 128x64 with 32x32x16 f16 MFMA (128 AGPR acc). BK=64, 64 KB LDS,
// single-buffered, 1 block/CU. Epilogue contracts channels with Wc, bias,
// ELU. Halved staging traffic vs BN=128 (A streamed 32x instead of 64x).
__global__ __launch_bounds__(512, 2) void gemm_fused_kernel(
    const _Float16* __restrict__ A, const _Float16* __restrict__ B,
    const float* __restrict__ Wc, const float* __restrict__ bias,
    float* __restrict__ out) {
  __shared__ _Float16 As[BM * BK];  // 32 KB
  __shared__ _Float16 Bs[BN * BK];  // 32 KB

  // XCD swizzle: xcd = bid&7; each XCD owns 4 n-tiles (B panel 2.75 MB,
  // L2-resident); 4 consecutive blocks share one A-tile.
  const int bid = blockIdx.x;  // 0..2047
  const int l = bid >> 3;      // 0..255
  const int ntile = (bid & 7) * 4 + (l & 3);  // 0..31
  const int mtile = l >> 2;                   // 0..63

  const int t = threadIdx.x;
  const int lane = t & 63;
  const int wave = t >> 6;                  // 0..7
  const int wm = wave >> 2, wn = wave & 3;  // 2 x 4; wave tile 128(M)x64(N)
  const int r32 = lane & 31, hh = lane >> 5;

  f32x16 acc[4][2] = {};  // [mb][nb]: mb 4x32 rows, nb 2x32 cols

  const _Float16* sA = A + (size_t)mtile * TILE_H + t * 8;
  const _Float16* sB = B + (size_t)ntile * TILE_H + t * 8;
  _Float16* lA = As + t * 8;
  _Float16* lB = Bs + t * 8;

  for (int it = 0; it < KITER; it++) {
#pragma unroll
    for (int i = 0; i < 4; i++) async_copy16(sA + i * 4096, lA + i * 4096);
#pragma unroll
    for (int i = 0; i < 4; i++) async_copy16(sB + i * 4096, lB + i * 4096);
    sA += CH_PER_IT * 8;
    sB += CH_PER_IT * 8;
    __syncthreads();

#pragma unroll
    for (int ks = 0; ks < 4; ks++) {
      const int cc = 2 * ks + hh;  // A/B operand k-half for this substep
      half8 bf[2];
#pragma unroll
      for (int nb = 0; nb < 2; nb++) {
        const int r = wn * 64 + nb * 32 + r32;
        bf[nb] = *(const half8*)(Bs + r * 64 + ((cc + r) & 7) * 8);
      }
#pragma unroll
      for (int mb = 0; mb < 4; mb++) {
        const int r = wm * 128 + mb * 32 + r32;
        const half8 af = *(const half8*)(As + r * 64 + ((cc + r) & 7) * 8);
#pragma unroll
        for (int nb = 0; nb < 2; nb++)
          acc[mb][nb] = __builtin_amdgcn_mfma_f32_32x32x16_f16(
              af, bf[nb], acc[mb][nb], 0, 0, 0);
      }
    }
    __syncthreads();
  }

  // Epilogue. C/D 32x32 layout: col = lane&31, row = (reg&3)+8*(reg>>2)+4*hh.
  // Wave's 128 M-rows = 2 images x 64 channels; mb 0,1 -> img0, mb 2,3 -> img1.
  const int ibase = mtile * 4 + wm * 2;
  float v[2][2];  // [img][nb]
#pragma unroll
  for (int nb = 0; nb < 2; nb++) {
    const int n_g = ntile * BN + wn * 64 + nb * 32 + r32;
    const float* wc = Wc + (size_t)n_g * NCONV;
    f32x4 w[2][4];
#pragma unroll
    for (int hf = 0; hf < 2; hf++)
#pragma unroll
      for (int g = 0; g < 4; g++)
        w[hf][g] = *(const f32x4*)(wc + hf * 32 + hh * 4 + g * 8);
#pragma unroll
    for (int img = 0; img < 2; img++) {
      float p = 0.f;
#pragma unroll
      for (int hf = 0; hf < 2; hf++)
#pragma unroll
        for (int g = 0; g < 4; g++)
#pragma unroll
          for (int q = 0; q < 4; q++)
            p += acc[img * 2 + hf][nb][g * 4 + q] * w[hf][g][q];
      p += __shfl_xor(p, 32);  // combine the two row-halves (hh)
      v[img][nb] = p;
    }
  }
  const int img = ibase + hh;  // lane writes its own half's image
#pragma unroll
  for (int nb = 0; nb < 2; nb++) {
    const int n_out = ntile * BN + wn * 64 + nb * 32 + r32;
    float z = v[hh][nb] * 0.00390625f + bias[n_out];  // undo x256 scaling
    z = z > 0.f ? z : (__expf(z) - 1.f);
    out[(size_t)img * NNEUR + n_out] = z;
  }
}

extern "C" void kernel_launch(void* const* d_in, const int* in_sizes, int n_in,
                              void* d_out, int out_size, void* d_ws,
                              size_t ws_size, hipStream_t stream) {
  const float* conv = (const float*)d_in[0];
  const float* Wc = (const float*)d_in[1];
  const float* Wy = (const float*)d_in[2];
  const float* Wx = (const float*)d_in[3];
  const float* bias = (const float*)d_in[4];
  float* out = (float*)d_out;

  _Float16* Abuf = (_Float16*)d_ws;  // 64 tiles * 344064 halfs = 44.0 MB
  _Float16* Bbuf =
      (_Float16*)((char*)d_ws + (size_t)A_NTILES * TILE_H * 2);  // 22.0 MB

  prep_kernel<<<A_PREP_BLOCKS + B_PREP_BLOCKS, 256, 0, stream>>>(conv, Wy, Wx,
                                                                 Abuf, Bbuf);
  gemm_fused_kernel<<<2048, 512, 0, stream>>>(Abuf, Bbuf, Wc, bias, out);
}